// Round 1
// 533.392 us; speedup vs baseline: 1.1771x; 1.1771x over previous
//
#include <hip/hip_runtime.h>
#include <stdint.h>

#define K_DIM 4096
#define N_DIM 4096
#define KS_DIM (K_DIM / 32)   // 128 k-steps
#define NT_DIM (N_DIM / 16)   // 256 n-tiles

typedef __attribute__((ext_vector_type(8))) short s16x8;
typedef __attribute__((ext_vector_type(4))) float f32x4;

static __device__ __forceinline__ unsigned short f32_to_bf16(float f) {
    union { float f; unsigned int u; } v; v.f = f;
    unsigned int u = v.u;
    u += 0x7FFFu + ((u >> 16) & 1u);   // RNE; inputs finite
    return (unsigned short)(u >> 16);
}

// ---------------------------------------------------------------------------
// Fragment pack layout (both operands): for 16x16x32 bf16 MFMA, lane L holds
// op[m_or_n = L&15][k = (L>>4)*8 + j], j=0..7.  We store each (tile, k-step)
// fragment as 64 lane-chunks of 16 B, in lane order:
//   pack[ ((ks * T + t) * 64 + L) * 8 ]   (T = M/16 or N/16, t = tile index)
// => LDS image after global_load_lds is base + L*16  => fragment ds_read is
//    perfectly linear (conflict-free), both A and B.
// ---------------------------------------------------------------------------

// x (M,K) f32 -> A-pack. One wave per (ks, mt) tile.
extern "C" __global__ void pack_x_k(const float* __restrict__ in,
                                    unsigned short* __restrict__ out, int MT) {
    int wid = blockIdx.x * 4 + (threadIdx.x >> 6);
    int lane = threadIdx.x & 63;
    int mt = wid % MT, ks = wid / MT;
    int r = lane & 15, q = lane >> 4;
    const float* src = in + (size_t)(mt * 16 + r) * K_DIM + ks * 32 + q * 8;
    float4 a = *(const float4*)src;
    float4 b = *(const float4*)(src + 4);
    s16x8 o;
    o[0] = (short)f32_to_bf16(a.x); o[1] = (short)f32_to_bf16(a.y);
    o[2] = (short)f32_to_bf16(a.z); o[3] = (short)f32_to_bf16(a.w);
    o[4] = (short)f32_to_bf16(b.x); o[5] = (short)f32_to_bf16(b.y);
    o[6] = (short)f32_to_bf16(b.z); o[7] = (short)f32_to_bf16(b.w);
    *(s16x8*)(out + ((size_t)wid * 64 + lane) * 8) = o;
}

// w_t (K,N) f32 -> B-pack via LDS transpose. Block handles 64k x 64n.
extern "C" __global__ void pack_w_k(const float* __restrict__ in,
                                    unsigned short* __restrict__ out) {
    __shared__ __align__(16) unsigned short tile[64][72];  // [n_local][k_local]
    int n0 = blockIdx.x * 64, k0 = blockIdx.y * 64;
    int t = threadIdx.x;
    int tr = t >> 4, tc = (t & 15) * 4;
#pragma unroll
    for (int i = 0; i < 4; ++i) {
        int k = tr + i * 16;
        float4 v = *(const float4*)(in + (size_t)(k0 + k) * N_DIM + n0 + tc);
        tile[tc + 0][k] = f32_to_bf16(v.x);
        tile[tc + 1][k] = f32_to_bf16(v.y);
        tile[tc + 2][k] = f32_to_bf16(v.z);
        tile[tc + 3][k] = f32_to_bf16(v.w);
    }
    __syncthreads();
    // 8 fragments per block: f = h*4 + ntl  (h = k-half, ntl = n-tile local)
    int f = t >> 5, h = f >> 2, ntl = f & 3;
    int ks = blockIdx.y * 2 + h;
    int nt = blockIdx.x * 4 + ntl;
    unsigned short* dst = out + ((size_t)(ks * NT_DIM + nt) * 64) * 8;
#pragma unroll
    for (int u = 0; u < 2; ++u) {
        int c = (t & 31) * 2 + u;            // lane-chunk index 0..63
        int r = c & 15, q = c >> 4;
        s16x8 o = *(const s16x8*)&tile[ntl * 16 + r][h * 32 + q * 8];
        *(s16x8*)(dst + (size_t)c * 8) = o;
    }
}

__device__ __forceinline__ void async_cp16(const unsigned short* g, unsigned short* l) {
    __builtin_amdgcn_global_load_lds(
        (const __attribute__((address_space(1))) unsigned int*)g,
        (__attribute__((address_space(3))) unsigned int*)l, 16, 0, 0);
}

// ---------------------------------------------------------------------------
// GEMM on packed operands. 256x256 tile, BK=32, 8 waves (2M x 4N), each wave
// owns 128x64 (8x4 frags of 16x16).  4-slot LDS ring (4 x 32 KB), counted
// vmcnt (never 0 in steady state), ONE raw s_barrier per K-step, stage for
// tile t+3 issued right after the barrier into the slot freed by body t-1.
// Race-freedom: a wave issues the stage only after the barrier that proves
// all waves finished body t-1 (their ds_reads were consumed by MFMAs that
// precede the barrier in program order); reads of tile t happen only after
// vmcnt(8) (own 4 tile-t loads retired) + barrier (everyone else's too).
// ---------------------------------------------------------------------------
#define SLOTS 4
#define SLOT_SHORTS (32 * 512)   // 16384 shorts = 32 KB per K-tile (16 A + 16 B frags)

__device__ __forceinline__ void sbar() {
    __builtin_amdgcn_sched_barrier(0);
    __builtin_amdgcn_s_barrier();
    __builtin_amdgcn_sched_barrier(0);
}

template <int VM>
__device__ __forceinline__ void wait_vm() {
    if constexpr (VM == 8)      asm volatile("s_waitcnt vmcnt(8)" ::: "memory");
    else if constexpr (VM == 4) asm volatile("s_waitcnt vmcnt(4)" ::: "memory");
    else                        asm volatile("s_waitcnt vmcnt(0)" ::: "memory");
    __builtin_amdgcn_sched_barrier(0);
}

#define BODY(T, VM, STAGE)                                                  \
  {                                                                         \
    wait_vm<VM>();                                                          \
    sbar();                                                                 \
    if (STAGE) {                                                            \
      unsigned short* d = lds + (((T) + 3) & 3) * SLOT_SHORTS + dsOff;      \
      _Pragma("unroll")                                                     \
      for (int fi = 0; fi < 4; ++fi)                                        \
        async_cp16(gstage + fi * 512, d + fi * 512);                        \
      gstage += strideS;                                                    \
    }                                                                       \
    const unsigned short* a = lds + ((T) & 3) * SLOT_SHORTS + aOff;         \
    const unsigned short* b = lds + ((T) & 3) * SLOT_SHORTS + bOff;         \
    s16x8 af[8], bf[4];                                                     \
    _Pragma("unroll")                                                       \
    for (int i = 0; i < 8; ++i) af[i] = *(const s16x8*)(a + i * 512);       \
    _Pragma("unroll")                                                       \
    for (int j = 0; j < 4; ++j) bf[j] = *(const s16x8*)(b + j * 512);       \
    __builtin_amdgcn_s_setprio(1);                                          \
    _Pragma("unroll")                                                       \
    for (int i = 0; i < 8; ++i)                                             \
      _Pragma("unroll")                                                     \
      for (int j = 0; j < 4; ++j)                                           \
        acc[i][j] = __builtin_amdgcn_mfma_f32_16x16x32_bf16(                \
            af[i], bf[j], acc[i][j], 0, 0, 0);                              \
    __builtin_amdgcn_s_setprio(0);                                          \
  }

extern "C" __global__ __launch_bounds__(512, 2)
void gemm_pk(const unsigned short* __restrict__ Ap,
             const unsigned short* __restrict__ Bp,
             float* __restrict__ C, int M) {
    __shared__ __align__(16) unsigned short lds[SLOTS * SLOT_SHORTS];  // 128 KB
    const int MT = M >> 4;
    const int tid = threadIdx.x;
    const int wave = tid >> 6, lane = tid & 63;

    // T1: bijective XCD-aware swizzle of the linear block id (nwg % 8 == 0)
    const int nwg = gridDim.x;
    const int cpx = nwg >> 3;
    const int swz = (blockIdx.x & 7) * cpx + (blockIdx.x >> 3);
    const int bn = swz & (N_DIM / 256 - 1);   // N/256 = 16
    const int bm = swz >> 4;

    const int wm2 = wave >> 2;   // 0..1 : m-half, also staging role (0=A, 1=B)
    const int wn4 = wave & 3;    // 0..3 : n-quarter
    const int fr0 = (wave & 3) * 4;  // fragment group this wave stages

    // staging pointers: waves 0-3 stage A frags [4w..4w+3], waves 4-7 stage B
    const unsigned short* gstage = wm2
        ? Bp + (((size_t)bn * 16 + fr0) * 64 + lane) * 8
        : Ap + (((size_t)bm * 16 + fr0) * 64 + lane) * 8;
    const size_t strideS = (size_t)(wm2 ? NT_DIM : MT) * 512;
    const int dsOff = (wm2 * 16 + fr0) * 512;         // wave-uniform LDS dst

    // compute-read bases (lane-linear => conflict-free b128)
    const int aOff = (wm2 * 8) * 512 + lane * 8;
    const int bOff = (16 + wn4 * 4) * 512 + lane * 8;

    f32x4 acc[8][4] = {};

    // prologue: stage tiles 0..2 into slots 0..2 (12 loads in flight per wave)
#pragma unroll
    for (int t = 0; t < SLOTS - 1; ++t) {
        unsigned short* d = lds + t * SLOT_SHORTS + dsOff;
#pragma unroll
        for (int fi = 0; fi < 4; ++fi)
            async_cp16(gstage + fi * 512, d + fi * 512);
        gstage += strideS;
    }

    for (int t = 0; t < KS_DIM - 2; ++t)
        BODY(t, 8, (t + 3 < KS_DIM));
    BODY(KS_DIM - 2, 4, false);
    BODY(KS_DIM - 1, 0, false);

    // epilogue: C/D layout col=lane&15, row=(lane>>4)*4+reg (m89-verified)
    const size_t tileM = (size_t)bm * 256, tileN = (size_t)bn * 256;
#pragma unroll
    for (int i = 0; i < 8; ++i)
#pragma unroll
        for (int j = 0; j < 4; ++j) {
            size_t row = tileM + wm2 * 128 + i * 16 + (lane >> 4) * 4;
            size_t col = tileN + wn4 * 64 + j * 16 + (lane & 15);
#pragma unroll
            for (int r = 0; r < 4; ++r)
                C[(row + r) * N_DIM + col] = acc[i][j][r];
        }
}

// ---- fallback (ws too small): convert f32->bf16 inline while staging ----
extern "C" __global__ __launch_bounds__(256)
void gemm_f32_k(const float* __restrict__ X,   // (M,K)
                const float* __restrict__ Wt,  // (K,N)
                float* __restrict__ C, int M) {
    const int K = K_DIM, N = N_DIM;
    __shared__ __align__(16) unsigned short sA[128 * 32];
    __shared__ __align__(16) unsigned short sB[128 * 32];
    const int tid = threadIdx.x;
    const int wave = tid >> 6, lane = tid & 63;
    const int wm = (wave >> 1) * 64, wn = (wave & 1) * 64;
    const size_t tileM = (size_t)blockIdx.y * 128, tileN = (size_t)blockIdx.x * 128;
    const int frow = lane & 15, fcol = (lane >> 4) * 8;
    f32x4 acc[4][4] = {};
    for (int k0 = 0; k0 < K; k0 += 32) {
        __syncthreads();
#pragma unroll
        for (int it = 0; it < 4; ++it) {
            int idx = it * 256 + tid;
            int m = idx >> 3, c4 = (idx & 7) * 4;
            float4 v = *(const float4*)(X + (tileM + m) * (size_t)K + k0 + c4);
            sA[m * 32 + c4 + 0] = f32_to_bf16(v.x);
            sA[m * 32 + c4 + 1] = f32_to_bf16(v.y);
            sA[m * 32 + c4 + 2] = f32_to_bf16(v.z);
            sA[m * 32 + c4 + 3] = f32_to_bf16(v.w);
        }
#pragma unroll
        for (int it = 0; it < 16; ++it) {
            int idx = it * 256 + tid;
            int k = idx >> 7, n = idx & 127;
            float v = Wt[(size_t)(k0 + k) * N + tileN + n];
            sB[n * 32 + k] = f32_to_bf16(v);
        }
        __syncthreads();
        s16x8 af[4], bfr[4];
#pragma unroll
        for (int i = 0; i < 4; ++i)
            af[i] = *(const s16x8*)(sA + (wm + i * 16 + frow) * 32 + fcol);
#pragma unroll
        for (int j = 0; j < 4; ++j)
            bfr[j] = *(const s16x8*)(sB + (wn + j * 16 + frow) * 32 + fcol);
#pragma unroll
        for (int i = 0; i < 4; ++i)
#pragma unroll
            for (int j = 0; j < 4; ++j)
                acc[i][j] = __builtin_amdgcn_mfma_f32_16x16x32_bf16(
                    af[i], bfr[j], acc[i][j], 0, 0, 0);
    }
#pragma unroll
    for (int i = 0; i < 4; ++i)
#pragma unroll
        for (int j = 0; j < 4; ++j) {
            size_t row = tileM + wm + i * 16 + (lane >> 4) * 4;
            size_t col = tileN + wn + j * 16 + (lane & 15);
#pragma unroll
            for (int r = 0; r < 4; ++r)
                C[(row + r) * N + col] = acc[i][j][r];
        }
}

extern "C" void kernel_launch(void* const* d_in, const int* in_sizes, int n_in,
                              void* d_out, int out_size, void* d_ws, size_t ws_size,
                              hipStream_t stream) {
    const float* x   = (const float*)d_in[0];
    const float* w_t = (const float*)d_in[4];   // (K,N) dequantized W^T, bit-exact
    float* out = (float*)d_out;
    const int K = K_DIM, N = N_DIM;
    const int M = in_sizes[0] / K;              // 8192
    const int MT = M / 16;
    const size_t need = (size_t)M * K * 2 + (size_t)N * K * 2;  // 96 MB
    if (ws_size >= need && (M % 256) == 0) {
        unsigned short* ap = (unsigned short*)d_ws;
        unsigned short* bp = ap + (size_t)M * K;
        int nwave = KS_DIM * MT;  // one wave per A fragment-tile
        hipLaunchKernelGGL(pack_x_k, dim3(nwave / 4), dim3(256), 0, stream,
                           x, ap, MT);
        hipLaunchKernelGGL(pack_w_k, dim3(N / 64, K / 64), dim3(256), 0, stream,
                           w_t, bp);
        hipLaunchKernelGGL(gemm_pk, dim3((M / 256) * (N / 256)), dim3(512), 0,
                           stream, ap, bp, out, M);
    } else {
        hipLaunchKernelGGL(gemm_f32_k, dim3(N / 128, M / 128), dim3(256), 0, stream,
                           x, w_t, out, M);
    }
}

// Round 2
// 517.377 us; speedup vs baseline: 1.2136x; 1.0310x over previous
//
#include <hip/hip_runtime.h>
#include <stdint.h>

#define K_DIM 4096
#define N_DIM 4096
#define KS_DIM (K_DIM / 32)   // 128 k-steps
#define NT_DIM (N_DIM / 16)   // 256 n-tiles

typedef __attribute__((ext_vector_type(8))) short s16x8;
typedef __attribute__((ext_vector_type(4))) float f32x4;

static __device__ __forceinline__ unsigned short f32_to_bf16(float f) {
    union { float f; unsigned int u; } v; v.f = f;
    unsigned int u = v.u;
    u += 0x7FFFu + ((u >> 16) & 1u);   // RNE; inputs finite
    return (unsigned short)(u >> 16);
}

// ---------------------------------------------------------------------------
// Fragment pack layout (both operands): for 16x16x32 bf16 MFMA, lane L holds
// op[m_or_n = L&15][k = (L>>4)*8 + j], j=0..7.  We store each (tile, k-step)
// fragment as 64 lane-chunks of 16 B, in lane order:
//   pack[ ((ks * T + t) * 64 + L) * 8 ]   (T = M/16 or N/16, t = tile index)
// => LDS image after global_load_lds is base + L*16  => fragment ds_read is
//    perfectly linear (conflict-free), both A and B.
// ---------------------------------------------------------------------------

// x (M,K) f32 -> A-pack via LDS. Block: 16 rows (one mt) x 1024 cols (32 ks).
// Reads fully-coalesced 4 KB lines; writes fully-coalesced 16 B chunks.
extern "C" __global__ __launch_bounds__(256)
void pack_x_k(const float* __restrict__ in,
              unsigned short* __restrict__ out, int MT) {
    __shared__ __align__(16) unsigned short tile[16][1032];  // +8 pad: 2-way only
    const int kc = blockIdx.x;          // 1024-col block (32 ks)
    const int mt = blockIdx.y;          // 16-row block
    const int t = threadIdx.x;
#pragma unroll
    for (int r = 0; r < 16; ++r) {
        float4 v = *(const float4*)(in + (size_t)(mt * 16 + r) * K_DIM
                                    + kc * 1024 + t * 4);
        tile[r][t * 4 + 0] = f32_to_bf16(v.x);
        tile[r][t * 4 + 1] = f32_to_bf16(v.y);
        tile[r][t * 4 + 2] = f32_to_bf16(v.z);
        tile[r][t * 4 + 3] = f32_to_bf16(v.w);
    }
    __syncthreads();
    // 32 frags x 64 chunks = 2048 chunks of 16 B; 8 per thread, coalesced.
#pragma unroll
    for (int i = 0; i < 8; ++i) {
        int chunk = i * 256 + t;
        int f = chunk >> 6, L = chunk & 63;
        int r = L & 15, q = L >> 4;
        s16x8 v = *(const s16x8*)&tile[r][f * 32 + q * 8];
        int ks = kc * 32 + f;
        *(s16x8*)(out + ((size_t)(ks * MT + mt) * 64 + L) * 8) = v;
    }
}

// w_t (K,N) f32 -> B-pack via LDS transpose. Block handles 64k x 64n.
extern "C" __global__ void pack_w_k(const float* __restrict__ in,
                                    unsigned short* __restrict__ out) {
    __shared__ __align__(16) unsigned short tile[64][72];  // [n_local][k_local]
    int n0 = blockIdx.x * 64, k0 = blockIdx.y * 64;
    int t = threadIdx.x;
    int tr = t >> 4, tc = (t & 15) * 4;
#pragma unroll
    for (int i = 0; i < 4; ++i) {
        int k = tr + i * 16;
        float4 v = *(const float4*)(in + (size_t)(k0 + k) * N_DIM + n0 + tc);
        tile[tc + 0][k] = f32_to_bf16(v.x);
        tile[tc + 1][k] = f32_to_bf16(v.y);
        tile[tc + 2][k] = f32_to_bf16(v.z);
        tile[tc + 3][k] = f32_to_bf16(v.w);
    }
    __syncthreads();
    int f = t >> 5, h = f >> 2, ntl = f & 3;
    int ks = blockIdx.y * 2 + h;
    int nt = blockIdx.x * 4 + ntl;
    unsigned short* dst = out + ((size_t)(ks * NT_DIM + nt) * 64) * 8;
#pragma unroll
    for (int u = 0; u < 2; ++u) {
        int c = (t & 31) * 2 + u;
        int r = c & 15, q = c >> 4;
        s16x8 o = *(const s16x8*)&tile[ntl * 16 + r][h * 32 + q * 8];
        *(s16x8*)(dst + (size_t)c * 8) = o;
    }
}

__device__ __forceinline__ void async_cp16(const unsigned short* g, unsigned short* l) {
    __builtin_amdgcn_global_load_lds(
        (const __attribute__((address_space(1))) unsigned int*)g,
        (__attribute__((address_space(3))) unsigned int*)l, 16, 0, 0);
}

// ---------------------------------------------------------------------------
// GEMM, phased schedule (T3+T4+T5). 256x256 tile, BK=32, 8 waves (2M x 4N),
// wave owns 128x64. 4-slot LDS ring (4 x 32 KB), counted vmcnt (never 0 in
// steady state), TWO raw barriers per 32-k tile, body split into 2 phases of
// 16 MFMA so each wave's ds_reads for phase p+1 issue while phase p's MFMAs
// drain async in the matrix pipe.
// Slot safety: stage for tile t+3 (slot (t-1)&3) is issued >=1 barrier after
// every wave's last read of tile t-1 was consumed (its lgkm(0) precedes that
// barrier), and the DMA's LDS write lands >=200cy after issue.
// Visibility: each wave waits vmcnt for its own tile-(t+1) stages in ph2,
// then the ph2 barrier makes tile t+1 collectively visible before t+1's reads.
// ---------------------------------------------------------------------------
#define SLOTS 4
#define SLOT_SHORTS (32 * 512)   // 32 KB per K-tile (16 A + 16 B frags)

__device__ __forceinline__ void sbar() {
    __builtin_amdgcn_sched_barrier(0);
    __builtin_amdgcn_s_barrier();
    __builtin_amdgcn_sched_barrier(0);
}

template <int VM>
__device__ __forceinline__ void wait_vm() {
    if constexpr (VM == 8)      asm volatile("s_waitcnt vmcnt(8)" ::: "memory");
    else if constexpr (VM == 4) asm volatile("s_waitcnt vmcnt(4)" ::: "memory");
    else if constexpr (VM == 0) asm volatile("s_waitcnt vmcnt(0)" ::: "memory");
    if constexpr (VM >= 0) __builtin_amdgcn_sched_barrier(0);
}

__device__ __forceinline__ void lgkm0() {
    asm volatile("s_waitcnt lgkmcnt(0)" ::: "memory");
    __builtin_amdgcn_sched_barrier(0);
}

// VM = vmcnt for the NEXT tile's visibility wait (in ph2); -1 = skip.
#define BODY(T, VM, STAGE)                                                  \
  {                                                                         \
    const unsigned short* a = lds + ((T) & 3) * SLOT_SHORTS + aOff;         \
    const unsigned short* b = lds + ((T) & 3) * SLOT_SHORTS + bOff;         \
    unsigned short* d = lds + (((T) + 3) & 3) * SLOT_SHORTS + dsOff;        \
    /* ---- phase 1 ---- */                                                 \
    s16x8 af[4], bf[4];                                                     \
    _Pragma("unroll")                                                       \
    for (int i = 0; i < 4; ++i) af[i] = *(const s16x8*)(a + i * 512);       \
    _Pragma("unroll")                                                       \
    for (int j = 0; j < 4; ++j) bf[j] = *(const s16x8*)(b + j * 512);       \
    if (STAGE) {                                                            \
      async_cp16(gstage + 0 * 512, d + 0 * 512);                            \
      async_cp16(gstage + 1 * 512, d + 1 * 512);                            \
    }                                                                       \
    sbar();                                                                 \
    lgkm0();                                                                \
    __builtin_amdgcn_s_setprio(1);                                          \
    _Pragma("unroll")                                                       \
    for (int i = 0; i < 4; ++i)                                             \
      _Pragma("unroll")                                                     \
      for (int j = 0; j < 4; ++j)                                           \
        acc[i][j] = __builtin_amdgcn_mfma_f32_16x16x32_bf16(                \
            af[i], bf[j], acc[i][j], 0, 0, 0);                              \
    __builtin_amdgcn_s_setprio(0);                                          \
    /* ---- phase 2 ---- */                                                 \
    s16x8 ag[4];                                                            \
    _Pragma("unroll")                                                       \
    for (int i = 0; i < 4; ++i) ag[i] = *(const s16x8*)(a + (4 + i) * 512); \
    if (STAGE) {                                                            \
      async_cp16(gstage + 2 * 512, d + 2 * 512);                            \
      async_cp16(gstage + 3 * 512, d + 3 * 512);                            \
      gstage += strideS;                                                    \
    }                                                                       \
    wait_vm<VM>();                                                          \
    sbar();                                                                 \
    lgkm0();                                                                \
    __builtin_amdgcn_s_setprio(1);                                          \
    _Pragma("unroll")                                                       \
    for (int i = 0; i < 4; ++i)                                             \
      _Pragma("unroll")                                                     \
      for (int j = 0; j < 4; ++j)                                           \
        acc[4 + i][j] = __builtin_amdgcn_mfma_f32_16x16x32_bf16(            \
            ag[i], bf[j], acc[4 + i][j], 0, 0, 0);                          \
    __builtin_amdgcn_s_setprio(0);                                          \
  }

extern "C" __global__ __launch_bounds__(512, 2)
void gemm_pk(const unsigned short* __restrict__ Ap,
             const unsigned short* __restrict__ Bp,
             float* __restrict__ C, int M) {
    __shared__ __align__(16) unsigned short lds[SLOTS * SLOT_SHORTS];  // 128 KB
    const int MT = M >> 4;
    const int tid = threadIdx.x;
    const int wave = tid >> 6, lane = tid & 63;

    // T1: bijective XCD-aware swizzle of the linear block id (nwg % 8 == 0)
    const int nwg = gridDim.x;
    const int cpx = nwg >> 3;
    const int swz = (blockIdx.x & 7) * cpx + (blockIdx.x >> 3);
    const int bn = swz & (N_DIM / 256 - 1);   // N/256 = 16
    const int bm = swz >> 4;

    const int wm2 = wave >> 2;   // 0..1 : m-half, also staging role (0=A, 1=B)
    const int wn4 = wave & 3;    // 0..3 : n-quarter
    const int fr0 = (wave & 3) * 4;  // fragment group this wave stages

    const unsigned short* gstage = wm2
        ? Bp + (((size_t)bn * 16 + fr0) * 64 + lane) * 8
        : Ap + (((size_t)bm * 16 + fr0) * 64 + lane) * 8;
    const size_t strideS = (size_t)(wm2 ? NT_DIM : MT) * 512;
    const int dsOff = (wm2 * 16 + fr0) * 512;         // wave-uniform LDS dst

    const int aOff = (wm2 * 8) * 512 + lane * 8;
    const int bOff = (16 + wn4 * 4) * 512 + lane * 8;

    f32x4 acc[8][4] = {};

    // prologue: stage tiles 0..2 into slots 0..2 (12 loads in flight per wave)
#pragma unroll
    for (int t = 0; t < SLOTS - 1; ++t) {
        unsigned short* d = lds + t * SLOT_SHORTS + dsOff;
#pragma unroll
        for (int fi = 0; fi < 4; ++fi)
            async_cp16(gstage + fi * 512, d + fi * 512);
        gstage += strideS;
    }
    wait_vm<8>();   // tile 0 landed (own loads)
    sbar();         // collectively visible

    for (int t = 0; t < KS_DIM - 3; ++t)   // t = 0..124; stages tiles 3..127
        BODY(t, 8, true);
    BODY(KS_DIM - 3, 4, false);            // t = 125: wait tile 126
    BODY(KS_DIM - 2, 0, false);            // t = 126: wait tile 127
    BODY(KS_DIM - 1, -1, false);           // t = 127: nothing outstanding

    // epilogue: C/D layout col=lane&15, row=(lane>>4)*4+reg (m89-verified)
    const size_t tileM = (size_t)bm * 256, tileN = (size_t)bn * 256;
#pragma unroll
    for (int i = 0; i < 8; ++i)
#pragma unroll
        for (int j = 0; j < 4; ++j) {
            size_t row = tileM + wm2 * 128 + i * 16 + (lane >> 4) * 4;
            size_t col = tileN + wn4 * 64 + j * 16 + (lane & 15);
#pragma unroll
            for (int r = 0; r < 4; ++r)
                C[(row + r) * N_DIM + col] = acc[i][j][r];
        }
}

// ---- fallback (ws too small): convert f32->bf16 inline while staging ----
extern "C" __global__ __launch_bounds__(256)
void gemm_f32_k(const float* __restrict__ X,   // (M,K)
                const float* __restrict__ Wt,  // (K,N)
                float* __restrict__ C, int M) {
    const int K = K_DIM, N = N_DIM;
    __shared__ __align__(16) unsigned short sA[128 * 32];
    __shared__ __align__(16) unsigned short sB[128 * 32];
    const int tid = threadIdx.x;
    const int wave = tid >> 6, lane = tid & 63;
    const int wm = (wave >> 1) * 64, wn = (wave & 1) * 64;
    const size_t tileM = (size_t)blockIdx.y * 128, tileN = (size_t)blockIdx.x * 128;
    const int frow = lane & 15, fcol = (lane >> 4) * 8;
    f32x4 acc[4][4] = {};
    for (int k0 = 0; k0 < K; k0 += 32) {
        __syncthreads();
#pragma unroll
        for (int it = 0; it < 4; ++it) {
            int idx = it * 256 + tid;
            int m = idx >> 3, c4 = (idx & 7) * 4;
            float4 v = *(const float4*)(X + (tileM + m) * (size_t)K + k0 + c4);
            sA[m * 32 + c4 + 0] = f32_to_bf16(v.x);
            sA[m * 32 + c4 + 1] = f32_to_bf16(v.y);
            sA[m * 32 + c4 + 2] = f32_to_bf16(v.z);
            sA[m * 32 + c4 + 3] = f32_to_bf16(v.w);
        }
#pragma unroll
        for (int it = 0; it < 16; ++it) {
            int idx = it * 256 + tid;
            int k = idx >> 7, n = idx & 127;
            float v = Wt[(size_t)(k0 + k) * N + tileN + n];
            sB[n * 32 + k] = f32_to_bf16(v);
        }
        __syncthreads();
        s16x8 af[4], bfr[4];
#pragma unroll
        for (int i = 0; i < 4; ++i)
            af[i] = *(const s16x8*)(sA + (wm + i * 16 + frow) * 32 + fcol);
#pragma unroll
        for (int j = 0; j < 4; ++j)
            bfr[j] = *(const s16x8*)(sB + (wn + j * 16 + frow) * 32 + fcol);
#pragma unroll
        for (int i = 0; i < 4; ++i)
#pragma unroll
            for (int j = 0; j < 4; ++j)
                acc[i][j] = __builtin_amdgcn_mfma_f32_16x16x32_bf16(
                    af[i], bfr[j], acc[i][j], 0, 0, 0);
    }
#pragma unroll
    for (int i = 0; i < 4; ++i)
#pragma unroll
        for (int j = 0; j < 4; ++j) {
            size_t row = tileM + wm + i * 16 + (lane >> 4) * 4;
            size_t col = tileN + wn + j * 16 + (lane & 15);
#pragma unroll
            for (int r = 0; r < 4; ++r)
                C[(row + r) * N + col] = acc[i][j][r];
        }
}

extern "C" void kernel_launch(void* const* d_in, const int* in_sizes, int n_in,
                              void* d_out, int out_size, void* d_ws, size_t ws_size,
                              hipStream_t stream) {
    const float* x   = (const float*)d_in[0];
    const float* w_t = (const float*)d_in[4];   // (K,N) dequantized W^T, bit-exact
    float* out = (float*)d_out;
    const int K = K_DIM, N = N_DIM;
    const int M = in_sizes[0] / K;              // 8192
    const int MT = M / 16;
    const size_t need = (size_t)M * K * 2 + (size_t)N * K * 2;  // 96 MB
    if (ws_size >= need && (M % 256) == 0) {
        unsigned short* ap = (unsigned short*)d_ws;
        unsigned short* bp = ap + (size_t)M * K;
        hipLaunchKernelGGL(pack_x_k, dim3(K / 1024, M / 16), dim3(256), 0, stream,
                           x, ap, MT);
        hipLaunchKernelGGL(pack_w_k, dim3(N / 64, K / 64), dim3(256), 0, stream,
                           w_t, bp);
        hipLaunchKernelGGL(gemm_pk, dim3((M / 256) * (N / 256)), dim3(512), 0,
                           stream, ap, bp, out, M);
    } else {
        hipLaunchKernelGGL(gemm_f32_k, dim3(N / 128, M / 128), dim3(256), 0, stream,
                           x, w_t, out, M);
    }
}